// Round 2
// baseline (590.385 us; speedup 1.0000x reference)
//
#include <hip/hip_runtime.h>
#include <stdint.h>

// Problem constants
#define BB 16384
#define II 512
#define HH 1024
#define OO 512

typedef short s16x8 __attribute__((ext_vector_type(8)));
typedef float f32x4 __attribute__((ext_vector_type(4)));

__device__ __forceinline__ unsigned short f2bf(float x) {
  union { float f; unsigned u; } v; v.f = x;
  return (unsigned short)((v.u + 0x7fffu + ((v.u >> 16) & 1u)) >> 16);  // RNE
}
__device__ __forceinline__ float bf2f(unsigned short b) {
  union { unsigned u; float f; } v; v.u = ((unsigned)b) << 16;
  return v.f;
}
__device__ __forceinline__ float sigmoid_f(float x) {
  return 1.0f / (1.0f + __expf(-x));
}
__device__ __forceinline__ float tanh_f(float x) {
  float ax = fabsf(x);
  float e = __expf(-2.0f * ax);
  float t = (1.0f - e) / (1.0f + e);
  return x >= 0.0f ? t : -t;
}

// async global->LDS, 16B per lane, LDS dest = wave-uniform base + lane*16
__device__ __forceinline__ void stage16(const void* g, void* l) {
  __builtin_amdgcn_global_load_lds((const __attribute__((address_space(1))) void*)g,
                                   (__attribute__((address_space(3))) void*)l,
                                   16, 0, 0);
}

// ---- 128-tile helper (kept for gemm_out) ----
__device__ __forceinline__ void mma_step64(const unsigned short* As, const unsigned short* Bs,
                                           f32x4 acc[4][4], int lane, int wave) {
  const int wm = wave & 1, wn = wave >> 1;
  const int ln = lane & 15, q = lane >> 4;
#pragma unroll
  for (int s = 0; s < 2; ++s) {
    s16x8 af[4], bfr[4];
#pragma unroll
    for (int i = 0; i < 4; ++i) {
      const int r = wm * 64 + i * 16 + ln;
      af[i] = *(const s16x8*)(As + r * 64 + ((((s << 2) + q) + r) & 7) * 8);
    }
#pragma unroll
    for (int i = 0; i < 4; ++i) {
      const int r = wn * 64 + i * 16 + ln;
      bfr[i] = *(const s16x8*)(Bs + r * 64 + ((((s << 2) + q) + r) & 7) * 8);
    }
#pragma unroll
    for (int mi = 0; mi < 4; ++mi)
#pragma unroll
      for (int ni = 0; ni < 4; ++ni)
        acc[mi][ni] = __builtin_amdgcn_mfma_f32_16x16x32_bf16(af[mi], bfr[ni], acc[mi][ni], 0, 0, 0);
  }
}

// ---------------- prep kernels ----------------

__global__ __launch_bounds__(256) void prep_X(const float* __restrict__ inp,
                                              const float* __restrict__ h,
                                              unsigned short* __restrict__ Xb,
                                              unsigned short* __restrict__ Hlo) {
  int t = blockIdx.x * 256 + threadIdx.x;
  int base = t * 8;
  int b = base / 1536;
  int k = base - b * 1536;
  const float* src = (k < 512) ? (inp + b * 512 + k) : (h + b * 1024 + (k - 512));
  float4 v0 = *(const float4*)src;
  float4 v1 = *(const float4*)(src + 4);
  float f[8] = {v0.x, v0.y, v0.z, v0.w, v1.x, v1.y, v1.z, v1.w};
  unsigned short hi[8];
#pragma unroll
  for (int i = 0; i < 8; ++i) hi[i] = f2bf(f[i]);
  *(s16x8*)(Xb + base) = *(s16x8*)hi;
  if (k >= 512) {
    unsigned short lo[8];
#pragma unroll
    for (int i = 0; i < 8; ++i) lo[i] = f2bf(f[i] - bf2f(hi[i]));
    *(s16x8*)(Hlo + b * 1024 + (k - 512)) = *(s16x8*)lo;
  }
}

// Gate weights -> bf16 [4096][1536], K-contiguous, columns permuted for BN=256:
// n = blkX*256 + wn*64 + gate*16 + ln  <->  unit = blkX*64 + wn*16 + ln
__global__ __launch_bounds__(256) void prep_Wg(const float* __restrict__ Wx,
                                               const float* __restrict__ Wh,
                                               unsigned short* __restrict__ Wg) {
  int t = blockIdx.x * 256 + threadIdx.x;
  int base = t * 8;
  int n = base / 1536;
  int k = base - n * 1536;
  int r = n & 255;
  int gate = (r >> 4) & 3;
  int unit = ((n >> 8) << 6) + (((r >> 6) & 3) << 4) + (r & 15);
  const float* src = (k < 512) ? (Wx + (gate * 1024 + unit) * 512 + k)
                               : (Wh + (gate * 1024 + unit) * 1024 + (k - 512));
  float4 v0 = *(const float4*)src;
  float4 v1 = *(const float4*)(src + 4);
  float f[8] = {v0.x, v0.y, v0.z, v0.w, v1.x, v1.y, v1.z, v1.w};
  unsigned short o[8];
#pragma unroll
  for (int i = 0; i < 8; ++i) o[i] = f2bf(f[i]);
  *(s16x8*)(Wg + base) = *(s16x8*)o;
}

// z-correction weights [1024][2048]: k<1024 -> W_lo(Whz), k>=1024 -> W_hi(Whz)
__global__ __launch_bounds__(256) void prep_Wz2(const float* __restrict__ Whz,
                                                unsigned short* __restrict__ Wz2) {
  int t = blockIdx.x * 256 + threadIdx.x;
  int base = t * 8;
  int n = base >> 11;
  int k = base & 2047;
  int klo = (k < 1024) ? k : (k - 1024);
  const float* src = Whz + n * 1024 + klo;
  float4 v0 = *(const float4*)src;
  float4 v1 = *(const float4*)(src + 4);
  float f[8] = {v0.x, v0.y, v0.z, v0.w, v1.x, v1.y, v1.z, v1.w};
  unsigned short o[8];
  if (k < 1024) {
#pragma unroll
    for (int i = 0; i < 8; ++i) { unsigned short h_ = f2bf(f[i]); o[i] = f2bf(f[i] - bf2f(h_)); }
  } else {
#pragma unroll
    for (int i = 0; i < 8; ++i) o[i] = f2bf(f[i]);
  }
  *(s16x8*)(Wz2 + base) = *(s16x8*)o;
}

__global__ __launch_bounds__(256) void prep_Wout(const float* __restrict__ Wout,
                                                 unsigned short* __restrict__ Wo) {
  int t = blockIdx.x * 256 + threadIdx.x;
  int base = t * 8;
  float4 v0 = *(const float4*)(Wout + base);
  float4 v1 = *(const float4*)(Wout + base + 4);
  float f[8] = {v0.x, v0.y, v0.z, v0.w, v1.x, v1.y, v1.z, v1.w};
  unsigned short o[8];
#pragma unroll
  for (int i = 0; i < 8; ++i) o[i] = f2bf(f[i]);
  *(s16x8*)(Wo + base) = *(s16x8*)o;
}

// ================= 256x256 / 8-wave / deep-prefetch GEMM machinery =================
//
// LDS: lds[buf][A=0/B=1][256*64 bf16]; per row r the logical 16B chunk j lives at
// slot (j+r)&7 (conflict-free, measured 0 conflicts).
//
// Per K-tile t (even; reads buf0; 4 phases):
//   q0: read B[all 8] + A[mi0-3] (16 ds_reads); bar; lgkm(0); MFMA mi0,1; bar
//   q1: read A[mi4-7] (8 ds_reads); stage B(t+2)->dB0;  bar; (no lgkm wait,
//       mi2,3 drained at q0); MFMA mi2,3; bar
//   q2: bar; lgkm(0) (~free, reads 1 phase old); MFMA mi4,5; bar
//   q3: stage A(t+2)->dA0; bar; MFMA mi6,7; vmcnt(8); bar
// Hazards: B(t+2) staged after q0's trailing bar (all B reads drained pre-bar);
// A(t+2) staged after q2's trailing bar (all A reads drained at q2's lgkm(0)).
// vmcnt(8) = exactly this tile's 8 stage-loads outstanding => A(t+1),B(t+1)
// (issued 5-7 phases ago, during tile t-1) certified complete. Never waits on
// same-tile loads (the round-1 stall). Drain vmcnt(0) only at tile NT-2.

#define RD_A(CA, MI, KS) (*(const s16x8*)((CA) + ((KS) ? aoff1 : aoff0) + (MI) * 1024))
#define RD_B(CB, NI, KS) (*(const s16x8*)((CB) + ((KS) ? boff1 : boff0) + (NI) * 1024))
#define VM8 asm volatile("s_waitcnt vmcnt(8)" ::: "memory")
#define VM0 asm volatile("s_waitcnt vmcnt(0)" ::: "memory")
#define LGKM0 asm volatile("s_waitcnt lgkmcnt(0)" ::: "memory")
#define VMNONE ((void)0)
#define NOST ((void)0)

#define ST_A2(TT, DB) do { \
  stage16(gA[0][0] + (size_t)(TT) * 64, (DB)); \
  stage16(gA[0][1] + (size_t)(TT) * 64, (DB) + 4096); \
  stage16(gA[1][0] + (size_t)(TT) * 64, (DB) + 8192); \
  stage16(gA[1][1] + (size_t)(TT) * 64, (DB) + 12288); } while (0)
#define ST_B2(TT, DB) do { \
  stage16(gB[0][0] + (size_t)(TT) * 64, (DB)); \
  stage16(gB[0][1] + (size_t)(TT) * 64, (DB) + 4096); \
  stage16(gB[1][0] + (size_t)(TT) * 64, (DB) + 8192); \
  stage16(gB[1][1] + (size_t)(TT) * 64, (DB) + 12288); } while (0)
// zcorr A source switches at tile 16 (h_hi from Xb, then h_lo from Hlo)
#define ZST_A2(TT, DB) do { \
  const unsigned short *z0_, *z1_, *z2_, *z3_; \
  if ((TT) < 16) { \
    z0_ = gAX[0][0] + (size_t)(TT) * 64; z1_ = gAX[0][1] + (size_t)(TT) * 64; \
    z2_ = gAX[1][0] + (size_t)(TT) * 64; z3_ = gAX[1][1] + (size_t)(TT) * 64; \
  } else { \
    const int tz_ = (TT) - 16; \
    z0_ = gAH[0][0] + (size_t)tz_ * 64; z1_ = gAH[0][1] + (size_t)tz_ * 64; \
    z2_ = gAH[1][0] + (size_t)tz_ * 64; z3_ = gAH[1][1] + (size_t)tz_ * 64; \
  } \
  stage16(z0_, (DB)); stage16(z1_, (DB) + 4096); \
  stage16(z2_, (DB) + 8192); stage16(z3_, (DB) + 12288); } while (0)

#define PH(Q, WAIT, A00, A01, A10, A11) do { \
  __builtin_amdgcn_s_barrier(); \
  WAIT; \
  __builtin_amdgcn_sched_barrier(0); \
  __builtin_amdgcn_s_setprio(1); \
  _Pragma("unroll") \
  for (int ni = 0; ni < 4; ++ni) { \
    acc[2 * (Q)    ][ni] = __builtin_amdgcn_mfma_f32_16x16x32_bf16(A00, bq0[ni], acc[2 * (Q)    ][ni], 0, 0, 0); \
    acc[2 * (Q) + 1][ni] = __builtin_amdgcn_mfma_f32_16x16x32_bf16(A01, bq0[ni], acc[2 * (Q) + 1][ni], 0, 0, 0); \
  } \
  _Pragma("unroll") \
  for (int ni = 0; ni < 4; ++ni) { \
    acc[2 * (Q)    ][ni] = __builtin_amdgcn_mfma_f32_16x16x32_bf16(A10, bq1[ni], acc[2 * (Q)    ][ni], 0, 0, 0); \
    acc[2 * (Q) + 1][ni] = __builtin_amdgcn_mfma_f32_16x16x32_bf16(A11, bq1[ni], acc[2 * (Q) + 1][ni], 0, 0, 0); \
  } \
  __builtin_amdgcn_s_setprio(0); \
} while (0)

#define KTILE2(CA, CB, SB2, SA2, VMX) do { \
  s16x8 bq0[4], bq1[4], p0[4], p1[4]; \
  _Pragma("unroll") \
  for (int ni = 0; ni < 4; ++ni) { bq0[ni] = RD_B(CB, ni, 0); bq1[ni] = RD_B(CB, ni, 1); } \
  _Pragma("unroll") \
  for (int mi = 0; mi < 4; ++mi) { p0[mi] = RD_A(CA, mi, 0); p1[mi] = RD_A(CA, mi, 1); } \
  PH(0, LGKM0, p0[0], p0[1], p1[0], p1[1]); \
  __builtin_amdgcn_s_barrier(); \
  s16x8 r0[4], r1[4]; \
  _Pragma("unroll") \
  for (int mi = 0; mi < 4; ++mi) { r0[mi] = RD_A(CA, 4 + mi, 0); r1[mi] = RD_A(CA, 4 + mi, 1); } \
  SB2; \
  PH(1, VMNONE, p0[2], p0[3], p1[2], p1[3]); \
  __builtin_amdgcn_s_barrier(); \
  PH(2, LGKM0, r0[0], r0[1], r1[0], r1[1]); \
  __builtin_amdgcn_s_barrier(); \
  SA2; \
  PH(3, VMNONE, r0[2], r0[3], r1[2], r1[3]); \
  VMX; \
  __builtin_amdgcn_s_barrier(); \
} while (0)

// Gate GEMM + fused LSTM epilogue. M=16384, N=4096 (permuted), K=1536, NT=24.
__global__ __launch_bounds__(512, 2) void gemm_gates2(const unsigned short* __restrict__ Xb,
                                                      const unsigned short* __restrict__ Wg,
                                                      const float* __restrict__ bx,
                                                      const float* __restrict__ cold,
                                                      const unsigned short* __restrict__ Dgz,
                                                      float* __restrict__ hnew,
                                                      unsigned short* __restrict__ hnewb) {
  __shared__ unsigned short lds[2][2][16384];   // 128 KiB
  const int tid = threadIdx.x;
  const int lane = tid & 63, wave = tid >> 6;
  const int wm = wave & 1, wn = wave >> 1;
  const int ln = lane & 15, qlane = lane >> 4;
  // bijective XCD swizzle (nwg=1024, 8 XCDs, q=128): co-resident blocks on one
  // XCD share A-panels (L2-hot) and stream B.
  const int fid = (int)(blockIdx.y * 16 + blockIdx.x);
  const int swz = ((fid & 7) << 7) + (fid >> 3);
  const int bxi = swz & 15, byi = swz >> 4;
  const int n0 = bxi << 8, m0 = byi << 8;
  const int sr = tid >> 3;
  const int j = ((tid & 7) - (sr & 7)) & 7;

  const unsigned short* gA[2][2];
  const unsigned short* gB[2][2];
#pragma unroll
  for (int hh = 0; hh < 2; ++hh)
#pragma unroll
    for (int u = 0; u < 2; ++u) {
      const int row = hh * 128 + u * 64 + sr;
      gA[hh][u] = Xb + (size_t)(m0 + row) * 1536 + j * 8;
      gB[hh][u] = Wg + (size_t)(n0 + row) * 1536 + j * 8;
    }
  unsigned short* const dA0 = &lds[0][0][0] + (tid & ~63) * 8;
  unsigned short* const dB0 = &lds[0][1][0] + (tid & ~63) * 8;
  unsigned short* const dA1 = &lds[1][0][0] + (tid & ~63) * 8;
  unsigned short* const dB1 = &lds[1][1][0] + (tid & ~63) * 8;
  const unsigned short* const lA0 = &lds[0][0][0];
  const unsigned short* const lB0 = &lds[0][1][0];
  const unsigned short* const lA1 = &lds[1][0][0];
  const unsigned short* const lB1 = &lds[1][1][0];
  const int sl0 = ((qlane + ln) & 7) * 8;
  const int sl1 = sl0 ^ 32;
  const int aoff0 = (wm * 128 + ln) * 64 + sl0;
  const int aoff1 = (wm * 128 + ln) * 64 + sl1;
  const int boff0 = (wn * 64 + ln) * 64 + sl0;
  const int boff1 = (wn * 64 + ln) * 64 + sl1;

  f32x4 acc[8][4] = {};

  // prologue: A(0),B(0) then A(1),B(1); wait for the first 8 only
  ST_A2(0, dA0); ST_B2(0, dB0);
  ST_A2(1, dA1); ST_B2(1, dB1);
  VM8;
  __builtin_amdgcn_s_barrier();

#pragma unroll 1
  for (int t = 0; t < 22; t += 2) {
    KTILE2(lA0, lB0, ST_B2(t + 2, dB0), ST_A2(t + 2, dA0), VM8);
    KTILE2(lA1, lB1, ST_B2(t + 3, dB1), ST_A2(t + 3, dA1), VM8);
  }
  KTILE2(lA0, lB0, NOST, NOST, VM0);
  KTILE2(lA1, lB1, NOST, NOST, VMNONE);

  // Epilogue: acc[mi][ni] is gate ni for unit = bxi*64 + wn*16 + ln.
  const int unit = (bxi << 6) + (wn << 4) + ln;
  const float bi = bx[unit];
  const float bo = bx[1024 + unit];
  const float bfg = bx[2048 + unit];
  const float bz = bx[3072 + unit];
#pragma unroll
  for (int mi = 0; mi < 8; ++mi) {
#pragma unroll
    for (int r = 0; r < 4; ++r) {
      const int b = m0 + wm * 128 + mi * 16 + qlane * 4 + r;
      const int idx = b * 1024 + unit;
      const float gi = acc[mi][0][r] + bi;
      const float go = acc[mi][1][r] + bo;
      const float gf = acc[mi][2][r] + bfg;
      const float gz = acc[mi][3][r] + bz + bf2f(Dgz[idx]);
      const float iv = sigmoid_f(gi);
      const float ov = sigmoid_f(go);
      const float fv = sigmoid_f(gf);
      const float zv = tanh_f(gz);
      const float cn = iv * zv + fv * cold[idx];
      const float hn = ov * tanh_f(cn);
      hnew[idx] = hn;
      hnewb[idx] = f2bf(hn);
    }
  }
}

// Dgz[b,u] = sum_k h_hi*W_lo + h_lo*W_hi. M=16384, N=1024, K=2048, NT=32.
__global__ __launch_bounds__(512, 2) void gemm_zcorr2(const unsigned short* __restrict__ Xb,
                                                      const unsigned short* __restrict__ Hlo,
                                                      const unsigned short* __restrict__ Wz2,
                                                      unsigned short* __restrict__ Dgz) {
  __shared__ unsigned short lds[2][2][16384];
  const int tid = threadIdx.x;
  const int lane = tid & 63, wave = tid >> 6;
  const int wm = wave & 1, wn = wave >> 1;
  const int ln = lane & 15, qlane = lane >> 4;
  // swizzle: nwg=256, q=32
  const int fid = (int)(blockIdx.y * 4 + blockIdx.x);
  const int swz = ((fid & 7) << 5) + (fid >> 3);
  const int bxi = swz & 3, byi = swz >> 2;
  const int n0 = bxi << 8, m0 = byi << 8;
  const int sr = tid >> 3;
  const int j = ((tid & 7) - (sr & 7)) & 7;

  const unsigned short* gAX[2][2];
  const unsigned short* gAH[2][2];
  const unsigned short* gB[2][2];
#pragma unroll
  for (int hh = 0; hh < 2; ++hh)
#pragma unroll
    for (int u = 0; u < 2; ++u) {
      const int row = hh * 128 + u * 64 + sr;
      gAX[hh][u] = Xb  + (size_t)(m0 + row) * 1536 + 512 + j * 8;
      gAH[hh][u] = Hlo + (size_t)(m0 + row) * 1024 + j * 8;
      gB[hh][u]  = Wz2 + (size_t)(n0 + row) * 2048 + j * 8;
    }
  unsigned short* const dA0 = &lds[0][0][0] + (tid & ~63) * 8;
  unsigned short* const dB0 = &lds[0][1][0] + (tid & ~63) * 8;
  unsigned short* const dA1 = &lds[1][0][0] + (tid & ~63) * 8;
  unsigned short* const dB1 = &lds[1][1][0] + (tid & ~63) * 8;
  const unsigned short* const lA0 = &lds[0][0][0];
  const unsigned short* const lB0 = &lds[0][1][0];
  const unsigned short* const lA1 = &lds[1][0][0];
  const unsigned short* const lB1 = &lds[1][1][0];
  const int sl0 = ((qlane + ln) & 7) * 8;
  const int sl1 = sl0 ^ 32;
  const int aoff0 = (wm * 128 + ln) * 64 + sl0;
  const int aoff1 = (wm * 128 + ln) * 64 + sl1;
  const int boff0 = (wn * 64 + ln) * 64 + sl0;
  const int boff1 = (wn * 64 + ln) * 64 + sl1;

  f32x4 acc[8][4] = {};

  ZST_A2(0, dA0); ST_B2(0, dB0);
  ZST_A2(1, dA1); ST_B2(1, dB1);
  VM8;
  __builtin_amdgcn_s_barrier();

#pragma unroll 1
  for (int t = 0; t < 30; t += 2) {
    KTILE2(lA0, lB0, ST_B2(t + 2, dB0), ZST_A2(t + 2, dA0), VM8);
    KTILE2(lA1, lB1, ST_B2(t + 3, dB1), ZST_A2(t + 3, dA1), VM8);
  }
  KTILE2(lA0, lB0, NOST, NOST, VM0);
  KTILE2(lA1, lB1, NOST, NOST, VMNONE);

#pragma unroll
  for (int mi = 0; mi < 8; ++mi) {
#pragma unroll
    for (int r = 0; r < 4; ++r) {
      const int b = m0 + wm * 128 + mi * 16 + qlane * 4 + r;
#pragma unroll
      for (int ni = 0; ni < 4; ++ni) {
        const int n = n0 + wn * 64 + ni * 16 + ln;
        Dgz[b * 1024 + n] = f2bf(acc[mi][ni][r]);
      }
    }
  }
}

// out = h_new @ Wout^T + bout. M=16384, N=512, K=1024. (kept 128-tile: N too
// small for a full 256^2 grid)
__global__ __launch_bounds__(256) void gemm_out(const unsigned short* __restrict__ Hb,
                                                const unsigned short* __restrict__ Wo,
                                                const float* __restrict__ bout,
                                                float* __restrict__ out) {
  __shared__ unsigned short As[8192];
  __shared__ unsigned short Bs[8192];
  // swizzle: nwg=512, q=64
  const int fid = (int)(blockIdx.y * 4 + blockIdx.x);
  const int swz = ((fid & 7) << 6) + (fid >> 3);
  const int n0 = (swz & 3) * 128;
  const int m0 = (swz >> 2) * 128;
  const int tid = threadIdx.x, lane = tid & 63, wave = tid >> 6;
  const unsigned short *ga[4], *gb[4];
  unsigned short *la[4], *lb[4];
#pragma unroll
  for (int u = 0; u < 4; ++u) {
    int p = u * 256 + tid;
    int r = p >> 3;
    int jj = ((p & 7) - r) & 7;
    ga[u] = Hb + (size_t)(m0 + r) * 1024 + jj * 8;
    gb[u] = Wo + (size_t)(n0 + r) * 1024 + jj * 8;
    la[u] = As + (u * 256 + (tid & ~63)) * 8;
    lb[u] = Bs + (u * 256 + (tid & ~63)) * 8;
  }
  f32x4 acc[4][4] = {};
  for (int kk = 0; kk < 16; ++kk) {
#pragma unroll
    for (int u = 0; u < 4; ++u) { stage16(ga[u], la[u]); stage16(gb[u], lb[u]); }
#pragma unroll
    for (int u = 0; u < 4; ++u) { ga[u] += 64; gb[u] += 64; }
    __syncthreads();
    mma_step64(As, Bs, acc, lane, wave);
    __syncthreads();
  }
  const int wm = wave & 1, wn = wave >> 1;
  const int ln = lane & 15, q = lane >> 4;
  float bo_[4];
#pragma unroll
  for (int ni = 0; ni < 4; ++ni) bo_[ni] = bout[n0 + wn * 64 + ni * 16 + ln];
#pragma unroll
  for (int mi = 0; mi < 4; ++mi) {
#pragma unroll
    for (int r = 0; r < 4; ++r) {
      const int b = m0 + wm * 64 + mi * 16 + q * 4 + r;
#pragma unroll
      for (int ni = 0; ni < 4; ++ni) {
        const int n = n0 + wn * 64 + ni * 16 + ln;
        out[b * 512 + n] = acc[mi][ni][r] + bo_[ni];
      }
    }
  }
}

extern "C" void kernel_launch(void* const* d_in, const int* in_sizes, int n_in,
                              void* d_out, int out_size, void* d_ws, size_t ws_size,
                              hipStream_t stream) {
  const float* inp  = (const float*)d_in[0];
  const float* h    = (const float*)d_in[1];
  const float* c    = (const float*)d_in[2];
  const float* Wx   = (const float*)d_in[3];
  const float* bx   = (const float*)d_in[4];
  const float* Wh   = (const float*)d_in[5];
  const float* Wout = (const float*)d_in[6];
  const float* bout = (const float*)d_in[7];

  float* out  = (float*)d_out;                       // [B, 512]
  float* hnew = out + (size_t)BB * OO;               // [B, 1024]

  char* ws = (char*)d_ws;
  unsigned short* Xb  = (unsigned short*)(ws);                  //  50,331,648 B
  unsigned short* Wg  = (unsigned short*)(ws + 50331648);       //  12,582,912 B
  unsigned short* Wo  = (unsigned short*)(ws + 62914560);       //   1,048,576 B
  unsigned short* Hb  = (unsigned short*)(ws + 63963136);       //  33,554,432 B
  unsigned short* Hlo = (unsigned short*)(ws + 97517568);       //  33,554,432 B
  unsigned short* Wz2 = (unsigned short*)(ws + 131072000);      //   4,194,304 B
  unsigned short* Dgz = (unsigned short*)(ws + 135266304);      //  33,554,432 B

  prep_X   <<<12288, 256, 0, stream>>>(inp, h, Xb, Hlo);
  prep_Wg  <<<3072,  256, 0, stream>>>(Wx, Wh, Wg);
  prep_Wz2 <<<1024,  256, 0, stream>>>(Wh + 3 * 1024 * 1024, Wz2);
  prep_Wout<<<256,   256, 0, stream>>>(Wout, Wo);
  gemm_zcorr2<<<dim3(4, 64),  512, 0, stream>>>(Xb, Hlo, Wz2, Dgz);
  gemm_gates2<<<dim3(16, 64), 512, 0, stream>>>(Xb, Wg, bx, c, Dgz, hnew, Hb);
  gemm_out  <<<dim3(4, 128),  256, 0, stream>>>(Hb, Wo, bout, out);
}